// Round 12
// baseline (95.079 us; speedup 1.0000x reference)
//
#include <hip/hip_runtime.h>

#define T_SEQ 4096
#define DMODEL 1024
#define NHEAD 16
#define HDIM 64
#define WIN 128

typedef __attribute__((ext_vector_type(8))) short bf16x8;
typedef __attribute__((ext_vector_type(4))) float f32x4;
typedef __attribute__((ext_vector_type(4))) unsigned short u16x4;

__device__ __forceinline__ unsigned short f2bf(float f) {
  unsigned int u = __builtin_bit_cast(unsigned int, f);
  return (unsigned short)((u + 0x7fffu + ((u >> 16) & 1u)) >> 16);
}

__device__ __forceinline__ void gload_lds16(const unsigned short* g,
                                            unsigned short* l) {
  __builtin_amdgcn_global_load_lds(
      (const __attribute__((address_space(1))) void*)g,
      (__attribute__((address_space(3))) void*)l, 16, 0, 0);
}

// ---------------- fused fp32 -> bf16 converts (one launch) ----------------
__global__ void convert_all(const float* __restrict__ x,
                            const float* __restrict__ w_in,
                            const float* __restrict__ w_out,
                            unsigned short* __restrict__ x_bf,
                            unsigned short* __restrict__ w_in_bf,
                            unsigned short* __restrict__ w_out_bf) {
  int stride = gridDim.x * blockDim.x;
  int t0 = blockIdx.x * blockDim.x + threadIdx.x;
#define CVT(SRC, DST, N4)                                          \
  for (int i = t0; i < (N4); i += stride) {                        \
    float4 v = reinterpret_cast<const float4*>(SRC)[i];            \
    u16x4 o;                                                       \
    o.x = f2bf(v.x); o.y = f2bf(v.y); o.z = f2bf(v.z); o.w = f2bf(v.w); \
    reinterpret_cast<u16x4*>(DST)[i] = o;                          \
  }
  CVT(x, x_bf, T_SEQ * DMODEL / 4)
  CVT(w_in, w_in_bf, 3 * DMODEL * DMODEL / 4)
  CVT(w_out, w_out_bf, DMODEL * DMODEL / 4)
#undef CVT
}

// ---- GEMM, 4-slot counted-vmcnt pipeline (T3/T4): C = A * B^T ------------
// K split into 32 slots of 32; slots staged 3 ahead into a 4-slot rotating
// LDS ring; per slot: {s_waitcnt vmcnt(2*SI); s_barrier; stage(s+3);
// ds_read; setprio(1) MFMA setprio(0)}. vmcnt never drains below 2*SI until
// the peeled tail (2SI/SI/0). 4 waves (2x2), wave-tile (BM/2)x(BN/2).
// LDS linear; global source chunk-swizzled c^=((row>>1)&3); reads XOR back
// -> <=2-way bank aliasing (free). 80KB LDS (qkv) -> 2 blocks/CU.
// EPI 0: qkv epilogue; EPI 1: out epilogue.
template <int EPI, int BM, int BN>
__device__ __forceinline__ void gemm_body(
    const unsigned short* __restrict__ A,
    const unsigned short* __restrict__ B,
    const float* __restrict__ bias,
    unsigned short* __restrict__ q_buf,
    unsigned short* __restrict__ k_buf,
    unsigned short* __restrict__ vt_buf,
    const float* __restrict__ x_res,
    float* __restrict__ out) {
  const int K = DMODEL;
  constexpr int NS = DMODEL / 32;            // 32 K-slots
  constexpr int SM = BM / 2, SN = BN / 2;    // per-wave spans
  constexpr int MR = SM / 16, NR = SN / 16;
  constexpr int AL = BM / 64, BL = BN / 64;  // stage 16B-loads per thread/slot
  constexpr int SI = AL + BL;                // vm-insts per thread per slot
  constexpr int SLOT_A = BM * 32, SLOT_B = BN * 32;  // elements per slot
  __shared__ __align__(16) unsigned short As[4 * SLOT_A];
  __shared__ __align__(16) unsigned short Bs[4 * SLOT_B];

  int tid = threadIdx.x;
  int lane = tid & 63, wave = tid >> 6;
  int wr = wave >> 1, wc = wave & 1;
  int lo = lane & 15, hi = lane >> 4;
  int t0 = blockIdx.y * BM, e0 = blockIdx.x * BN;

  f32x4 acc[MR][NR];
#pragma unroll
  for (int m = 0; m < MR; ++m)
#pragma unroll
    for (int n = 0; n < NR; ++n) acc[m][n] = (f32x4){0.f, 0.f, 0.f, 0.f};

  // stage geometry: slot chunk i = l*256+tid (16B); row = l*64 + (tid>>2);
  // chunk-in-row c = tid&3, fetched global chunk = c ^ ((row>>1)&3)
  // = (tid&3)^((tid>>3)&3) (l*64 doesn't affect the low swizzle bits).
  int srow = tid >> 2;
  int cswz = (tid & 3) ^ ((tid >> 3) & 3);
  const unsigned short* AG = A + (size_t)(t0 + srow) * K + cswz * 8;
  const unsigned short* BG = B + (size_t)(e0 + srow) * K + cswz * 8;
  unsigned short* ldsA = As + wave * 512;  // + l*2048 + slot*SLOT_A
  unsigned short* ldsB = Bs + wave * 512;

  auto stage = [&](int s) {
    int k0 = s * 32;
    int sl = s & 3;
#pragma unroll
    for (int l = 0; l < AL; ++l)
      gload_lds16(AG + (size_t)l * 64 * K + k0, ldsA + sl * SLOT_A + l * 2048);
#pragma unroll
    for (int l = 0; l < BL; ++l)
      gload_lds16(BG + (size_t)l * 64 * K + k0, ldsB + sl * SLOT_B + l * 2048);
  };

  auto compute = [&](int s) {
    int sl = s & 3;
    const unsigned short* Ab = As + sl * SLOT_A;
    const unsigned short* Bb = Bs + sl * SLOT_B;
    bf16x8 af[MR], bfr[NR];
#pragma unroll
    for (int m = 0; m < MR; ++m) {
      int row = wr * SM + m * 16 + lo;
      af[m] = *reinterpret_cast<const bf16x8*>(
          &Ab[row * 32 + (hi ^ ((row >> 1) & 3)) * 8]);
    }
#pragma unroll
    for (int n = 0; n < NR; ++n) {
      int row = wc * SN + n * 16 + lo;
      bfr[n] = *reinterpret_cast<const bf16x8*>(
          &Bb[row * 32 + (hi ^ ((row >> 1) & 3)) * 8]);
    }
    __builtin_amdgcn_s_setprio(1);
#pragma unroll
    for (int m = 0; m < MR; ++m)
#pragma unroll
      for (int n = 0; n < NR; ++n)
        acc[m][n] = __builtin_amdgcn_mfma_f32_16x16x32_bf16(af[m], bfr[n],
                                                            acc[m][n], 0, 0, 0);
    __builtin_amdgcn_s_setprio(0);
  };

  stage(0);
  stage(1);
  stage(2);
#define WB(NN) asm volatile("s_waitcnt vmcnt(" #NN ")\n\ts_barrier" ::: "memory")
  for (int s = 0; s < NS - 3; ++s) {  // s = 0..28, always stages s+3
    if constexpr (SI == 5) WB(10); else WB(6);
    stage(s + 3);
    compute(s);
  }
  if constexpr (SI == 5) WB(10); else WB(6);
  compute(NS - 3);
  if constexpr (SI == 5) WB(5); else WB(3);
  compute(NS - 2);
  WB(0);
  compute(NS - 1);
#undef WB

  int t0w = t0 + wr * SM;
  int e0w = e0 + wc * SN;
#pragma unroll
  for (int m = 0; m < MR; ++m) {
#pragma unroll
    for (int n = 0; n < NR; ++n) {
      int e = e0w + n * 16 + lo;
      float bv = bias[e];
      if (EPI == 0) {
        int part = e >> 10;
        int h = (e >> 6) & 15;
        int d = e & 63;
        if (part == 2) {
          int t = t0w + m * 16 + hi * 4;
          u16x4 pk;
          pk.x = f2bf(acc[m][n][0] + bv);
          pk.y = f2bf(acc[m][n][1] + bv);
          pk.z = f2bf(acc[m][n][2] + bv);
          pk.w = f2bf(acc[m][n][3] + bv);
          *reinterpret_cast<u16x4*>(&vt_buf[((size_t)(h * HDIM + d)) * T_SEQ + t]) = pk;
        } else {
          unsigned short* dst = (part == 0) ? q_buf : k_buf;
#pragma unroll
          for (int jj = 0; jj < 4; ++jj) {
            int t = t0w + m * 16 + hi * 4 + jj;
            dst[((size_t)h * T_SEQ + t) * HDIM + d] = f2bf(acc[m][n][jj] + bv);
          }
        }
      } else {
#pragma unroll
        for (int jj = 0; jj < 4; ++jj) {
          int t = t0w + m * 16 + hi * 4 + jj;
          size_t idxo = (size_t)t * DMODEL + e;
          out[idxo] = acc[m][n][jj] + bv + x_res[idxo];
        }
      }
    }
  }
}

__global__ __launch_bounds__(256) void qkv_gemm(
    const unsigned short* __restrict__ A, const unsigned short* __restrict__ B,
    const float* __restrict__ bias, unsigned short* __restrict__ q_buf,
    unsigned short* __restrict__ k_buf, unsigned short* __restrict__ vt_buf) {
  gemm_body<0, 128, 192>(A, B, bias, q_buf, k_buf, vt_buf, nullptr, nullptr);
}

__global__ __launch_bounds__(256) void out_gemm(
    const unsigned short* __restrict__ A, const unsigned short* __restrict__ B,
    const float* __restrict__ bias, const float* __restrict__ x_res,
    float* __restrict__ out) {
  gemm_body<1, 128, 64>(A, B, bias, nullptr, nullptr, nullptr, x_res, out);
}

// ---------------- windowed flash attention (QBLK=32, K+V prefetch) --------
// R11 structure (equal-best): 4 waves/block, 1 wave per (head, 32q) tile;
// K and V register-prefetched 1 tile ahead; no-max softmax; per-wave LDS P
// slices, no barriers; setprio around MFMA clusters.
__global__ __launch_bounds__(256) void win_attn(
    const unsigned short* __restrict__ q_buf,
    const unsigned short* __restrict__ k_buf,
    const unsigned short* __restrict__ vt_buf,
    unsigned short* __restrict__ ctx) {
  __shared__ __align__(16) unsigned short p_lds[4][2][16 * 40];
  int tid = threadIdx.x;
  int wave = tid >> 6;
  int lane = tid & 63;
  int lo = lane & 15, hi = lane >> 4;

  int id = blockIdx.x;
  int sw = (id & 7) * (512 / 8) + (id >> 3);
  int job = sw * 4 + wave;           // 2048 jobs
  int h = job >> 7;
  int q0 = (job & 127) * 32;
  const float SC = 0.18033688011112042f;  // (1/sqrt(64)) * log2(e)

  bf16x8 aq[2][2];
#pragma unroll
  for (int u = 0; u < 2; ++u) {
    const unsigned short* qrow =
        q_buf + ((size_t)h * T_SEQ + q0 + u * 16 + lo) * HDIM + hi * 8;
    aq[u][0] = *reinterpret_cast<const bf16x8*>(qrow);
    aq[u][1] = *reinterpret_cast<const bf16x8*>(qrow + 32);
  }

  float L[2][4] = {{0.f, 0.f, 0.f, 0.f}, {0.f, 0.f, 0.f, 0.f}};
  f32x4 o[2][4];
#pragma unroll
  for (int u = 0; u < 2; ++u)
#pragma unroll
    for (int n = 0; n < 4; ++n) o[u][n] = (f32x4){0.f, 0.f, 0.f, 0.f};

  int jstart = q0 - WIN; if (jstart < 0) jstart = 0;
  int jend = q0 + 32 + WIN; if (jend > T_SEQ) jend = T_SEQ;

  bf16x8 kc[2][2], vc[4];
#pragma unroll
  for (int c = 0; c < 2; ++c) {
    const unsigned short* kp =
        k_buf + ((size_t)h * T_SEQ + jstart + c * 16 + lo) * HDIM + hi * 8;
    kc[c][0] = *reinterpret_cast<const bf16x8*>(kp);
    kc[c][1] = *reinterpret_cast<const bf16x8*>(kp + 32);
  }
#pragma unroll
  for (int n = 0; n < 4; ++n)
    vc[n] = *reinterpret_cast<const bf16x8*>(
        vt_buf + ((size_t)(h * HDIM + n * 16 + lo)) * T_SEQ + jstart + hi * 8);

  for (int j0 = jstart; j0 < jend; j0 += 32) {
    int jn = (j0 + 32 < jend) ? j0 + 32 : jstart;
    bf16x8 kn[2][2], vn[4];
#pragma unroll
    for (int c = 0; c < 2; ++c) {
      const unsigned short* kp =
          k_buf + ((size_t)h * T_SEQ + jn + c * 16 + lo) * HDIM + hi * 8;
      kn[c][0] = *reinterpret_cast<const bf16x8*>(kp);
      kn[c][1] = *reinterpret_cast<const bf16x8*>(kp + 32);
    }
#pragma unroll
    for (int n = 0; n < 4; ++n)
      vn[n] = *reinterpret_cast<const bf16x8*>(
          vt_buf + ((size_t)(h * HDIM + n * 16 + lo)) * T_SEQ + jn + hi * 8);
#pragma unroll
    for (int u = 0; u < 2; ++u) {
#pragma unroll
      for (int c = 0; c < 2; ++c) {
        f32x4 z = (f32x4){0.f, 0.f, 0.f, 0.f};
        __builtin_amdgcn_s_setprio(1);
        z = __builtin_amdgcn_mfma_f32_16x16x32_bf16(aq[u][0], kc[c][0], z, 0, 0, 0);
        z = __builtin_amdgcn_mfma_f32_16x16x32_bf16(aq[u][1], kc[c][1], z, 0, 0, 0);
        __builtin_amdgcn_s_setprio(0);
        int kj = j0 + c * 16 + lo;
#pragma unroll
        for (int jq = 0; jq < 4; ++jq) {
          int q = q0 + u * 16 + hi * 4 + jq;
          bool ok = (q - kj <= WIN) && (kj - q <= WIN);
          float p = ok ? __builtin_amdgcn_exp2f(z[jq] * SC) : 0.f;
          L[u][jq] += p;
          p_lds[wave][u][(hi * 4 + jq) * 40 + c * 16 + lo] = f2bf(p);
        }
      }
    }
    bf16x8 pa[2];
    pa[0] = *reinterpret_cast<const bf16x8*>(&p_lds[wave][0][lo * 40 + hi * 8]);
    pa[1] = *reinterpret_cast<const bf16x8*>(&p_lds[wave][1][lo * 40 + hi * 8]);
    __builtin_amdgcn_s_setprio(1);
#pragma unroll
    for (int n = 0; n < 4; ++n) {
      o[0][n] = __builtin_amdgcn_mfma_f32_16x16x32_bf16(pa[0], vc[n], o[0][n], 0, 0, 0);
      o[1][n] = __builtin_amdgcn_mfma_f32_16x16x32_bf16(pa[1], vc[n], o[1][n], 0, 0, 0);
    }
    __builtin_amdgcn_s_setprio(0);
#pragma unroll
    for (int c = 0; c < 2; ++c) {
      kc[c][0] = kn[c][0];
      kc[c][1] = kn[c][1];
    }
#pragma unroll
    for (int n = 0; n < 4; ++n) vc[n] = vn[n];
  }
#pragma unroll
  for (int u = 0; u < 2; ++u)
#pragma unroll
    for (int jq = 0; jq < 4; ++jq) {
#pragma unroll
      for (int w = 1; w < 16; w <<= 1) L[u][jq] += __shfl_xor(L[u][jq], w, 64);
    }
#pragma unroll
  for (int u = 0; u < 2; ++u)
#pragma unroll
    for (int jq = 0; jq < 4; ++jq) {
      int t = q0 + u * 16 + hi * 4 + jq;
      float inv = 1.f / L[u][jq];
#pragma unroll
      for (int n = 0; n < 4; ++n)
        ctx[(size_t)t * DMODEL + h * HDIM + n * 16 + lo] = f2bf(o[u][n][jq] * inv);
    }
}

extern "C" void kernel_launch(void* const* d_in, const int* in_sizes, int n_in,
                              void* d_out, int out_size, void* d_ws, size_t ws_size,
                              hipStream_t stream) {
  const float* x = (const float*)d_in[0];
  const float* w_in = (const float*)d_in[1];
  const float* b_in = (const float*)d_in[2];
  const float* w_out = (const float*)d_in[3];
  const float* b_out = (const float*)d_in[4];
  float* out = (float*)d_out;

  char* ws = (char*)d_ws;
  size_t off = 0;
  auto take = [&](size_t bytes) {
    char* p = ws + off;
    off += (bytes + 255) & ~(size_t)255;
    return p;
  };
  unsigned short* x_bf = (unsigned short*)take((size_t)T_SEQ * DMODEL * 2);
  unsigned short* w_in_bf = (unsigned short*)take((size_t)3 * DMODEL * DMODEL * 2);
  unsigned short* w_out_bf = (unsigned short*)take((size_t)DMODEL * DMODEL * 2);
  unsigned short* q_buf = (unsigned short*)take((size_t)T_SEQ * DMODEL * 2);
  unsigned short* k_buf = (unsigned short*)take((size_t)T_SEQ * DMODEL * 2);
  unsigned short* vt_buf = (unsigned short*)take((size_t)T_SEQ * DMODEL * 2 + 8192);
  unsigned short* ctx = (unsigned short*)take((size_t)T_SEQ * DMODEL * 2);

  convert_all<<<2048, 256, 0, stream>>>(x, w_in, w_out, x_bf, w_in_bf, w_out_bf);

  // qkv: M=4096, N=3072, tile 128x192 -> grid (16, 32) = 512 blocks
  dim3 g1(3 * DMODEL / 192, T_SEQ / 128);
  qkv_gemm<<<g1, 256, 0, stream>>>(x_bf, w_in_bf, b_in, q_buf, k_buf, vt_buf);

  win_attn<<<512, 256, 0, stream>>>(q_buf, k_buf, vt_buf, ctx);

  // out-proj: M=4096, N=1024, tile 128x64 -> grid (16, 32) = 512 blocks
  dim3 g2(DMODEL / 64, T_SEQ / 128);
  out_gemm<<<g2, 256, 0, stream>>>(ctx, w_out_bf, b_out, x, out);
}

// Round 13
// 91.553 us; speedup vs baseline: 1.0385x; 1.0385x over previous
//
#include <hip/hip_runtime.h>

#define T_SEQ 4096
#define DMODEL 1024
#define NHEAD 16
#define HDIM 64
#define WIN 128

typedef __attribute__((ext_vector_type(8))) short bf16x8;
typedef __attribute__((ext_vector_type(4))) float f32x4;
typedef __attribute__((ext_vector_type(4))) unsigned short u16x4;

__device__ __forceinline__ unsigned short f2bf(float f) {
  unsigned int u = __builtin_bit_cast(unsigned int, f);
  return (unsigned short)((u + 0x7fffu + ((u >> 16) & 1u)) >> 16);
}

__device__ __forceinline__ void gload_lds16(const unsigned short* g,
                                            unsigned short* l) {
  __builtin_amdgcn_global_load_lds(
      (const __attribute__((address_space(1))) void*)g,
      (__attribute__((address_space(3))) void*)l, 16, 0, 0);
}

// ---------------- fused fp32 -> bf16 converts (one launch) ----------------
__global__ void convert_all(const float* __restrict__ x,
                            const float* __restrict__ w_in,
                            const float* __restrict__ w_out,
                            unsigned short* __restrict__ x_bf,
                            unsigned short* __restrict__ w_in_bf,
                            unsigned short* __restrict__ w_out_bf) {
  int stride = gridDim.x * blockDim.x;
  int t0 = blockIdx.x * blockDim.x + threadIdx.x;
#define CVT(SRC, DST, N4)                                          \
  for (int i = t0; i < (N4); i += stride) {                        \
    float4 v = reinterpret_cast<const float4*>(SRC)[i];            \
    u16x4 o;                                                       \
    o.x = f2bf(v.x); o.y = f2bf(v.y); o.z = f2bf(v.z); o.w = f2bf(v.w); \
    reinterpret_cast<u16x4*>(DST)[i] = o;                          \
  }
  CVT(x, x_bf, T_SEQ * DMODEL / 4)
  CVT(w_in, w_in_bf, 3 * DMODEL * DMODEL / 4)
  CVT(w_out, w_out_bf, DMODEL * DMODEL / 4)
#undef CVT
}

// ---- GEMM body (R7/R10-proven, frozen): counted double-buffer, BK=64 -----
// STAGE(t+1) before compute(t); one raw {vmcnt(0),lgkmcnt(0),s_barrier} per
// K-tile. LDS linear; global source pre-XOR-swizzled; reads XOR back
// (0 bank conflicts). EPI 0: qkv epilogue; EPI 1: out epilogue.
template <int EPI, int BM, int BN>
__device__ __forceinline__ void gemm_body(
    const unsigned short* __restrict__ A,
    const unsigned short* __restrict__ B,
    const float* __restrict__ bias,
    unsigned short* __restrict__ q_buf,
    unsigned short* __restrict__ k_buf,
    unsigned short* __restrict__ vt_buf,
    const float* __restrict__ x_res,
    float* __restrict__ out) {
  const int K = DMODEL;
  constexpr int NT = DMODEL / 64;           // 16 K-tiles
  constexpr int SM = BM / 2, SN = BN / 2;   // per-wave spans
  constexpr int MR = SM / 16, NR = SN / 16;
  constexpr int AL = BM / 32, BL = BN / 32; // 16B stage loads per thread
  __shared__ __align__(16) unsigned short As[2 * BM * 64];
  __shared__ __align__(16) unsigned short Bs[2 * BN * 64];

  int tid = threadIdx.x;
  int lane = tid & 63, wave = tid >> 6;
  int wr = wave >> 1, wc = wave & 1;
  int lo = lane & 15, hi = lane >> 4;
  int t0 = blockIdx.y * BM, e0 = blockIdx.x * BN;

  f32x4 acc[MR][NR];
#pragma unroll
  for (int m = 0; m < MR; ++m)
#pragma unroll
    for (int n = 0; n < NR; ++n) acc[m][n] = (f32x4){0.f, 0.f, 0.f, 0.f};

  int c8 = (tid & 7) ^ ((tid >> 3) & 7);
  int srow = tid >> 3;  // + l*32 per load
  const unsigned short* AbaseG = A + (size_t)(t0 + srow) * K + c8 * 8;
  const unsigned short* BbaseG = B + (size_t)(e0 + srow) * K + c8 * 8;
  unsigned short* ldsAu = As + wave * 512;
  unsigned short* ldsBu = Bs + wave * 512;

  auto stage = [&](int tt) {
    int k0 = tt * 64;
    int ab = (tt & 1) * (BM * 64);
    int bb = (tt & 1) * (BN * 64);
#pragma unroll
    for (int l = 0; l < AL; ++l)
      gload_lds16(AbaseG + (size_t)l * 32 * K + k0, ldsAu + l * 2048 + ab);
#pragma unroll
    for (int l = 0; l < BL; ++l)
      gload_lds16(BbaseG + (size_t)l * 32 * K + k0, ldsBu + l * 2048 + bb);
  };

  stage(0);
  asm volatile("s_waitcnt vmcnt(0) lgkmcnt(0)\n\ts_barrier" ::: "memory");

  for (int t = 0; t < NT; ++t) {
    if (t + 1 < NT) stage(t + 1);
    const unsigned short* Ab = As + (t & 1) * (BM * 64);
    const unsigned short* Bb = Bs + (t & 1) * (BN * 64);
    bf16x8 af[MR][2], bfr[NR][2];
#pragma unroll
    for (int m = 0; m < MR; ++m) {
      int row = wr * SM + m * 16 + lo;
#pragma unroll
      for (int ks = 0; ks < 2; ++ks)
        af[m][ks] = *reinterpret_cast<const bf16x8*>(
            &Ab[row * 64 + (((ks << 2) + hi) ^ (row & 7)) * 8]);
    }
#pragma unroll
    for (int n = 0; n < NR; ++n) {
      int row = wc * SN + n * 16 + lo;
#pragma unroll
      for (int ks = 0; ks < 2; ++ks)
        bfr[n][ks] = *reinterpret_cast<const bf16x8*>(
            &Bb[row * 64 + (((ks << 2) + hi) ^ (row & 7)) * 8]);
    }
#pragma unroll
    for (int ks = 0; ks < 2; ++ks)
#pragma unroll
      for (int m = 0; m < MR; ++m)
#pragma unroll
        for (int n = 0; n < NR; ++n)
          acc[m][n] = __builtin_amdgcn_mfma_f32_16x16x32_bf16(af[m][ks], bfr[n][ks],
                                                              acc[m][n], 0, 0, 0);
    asm volatile("s_waitcnt vmcnt(0) lgkmcnt(0)\n\ts_barrier" ::: "memory");
  }

  int t0w = t0 + wr * SM;
  int e0w = e0 + wc * SN;
#pragma unroll
  for (int m = 0; m < MR; ++m) {
#pragma unroll
    for (int n = 0; n < NR; ++n) {
      int e = e0w + n * 16 + lo;
      float bv = bias[e];
      if (EPI == 0) {
        int part = e >> 10;
        int h = (e >> 6) & 15;
        int d = e & 63;
        if (part == 2) {
          int t = t0w + m * 16 + hi * 4;
          u16x4 pk;
          pk.x = f2bf(acc[m][n][0] + bv);
          pk.y = f2bf(acc[m][n][1] + bv);
          pk.z = f2bf(acc[m][n][2] + bv);
          pk.w = f2bf(acc[m][n][3] + bv);
          *reinterpret_cast<u16x4*>(&vt_buf[((size_t)(h * HDIM + d)) * T_SEQ + t]) = pk;
        } else {
          unsigned short* dst = (part == 0) ? q_buf : k_buf;
#pragma unroll
          for (int jj = 0; jj < 4; ++jj) {
            int t = t0w + m * 16 + hi * 4 + jj;
            dst[((size_t)h * T_SEQ + t) * HDIM + d] = f2bf(acc[m][n][jj] + bv);
          }
        }
      } else {
#pragma unroll
        for (int jj = 0; jj < 4; ++jj) {
          int t = t0w + m * 16 + hi * 4 + jj;
          size_t idxo = (size_t)t * DMODEL + e;
          out[idxo] = acc[m][n][jj] + bv + x_res[idxo];
        }
      }
    }
  }
}

__global__ __launch_bounds__(256) void qkv_gemm(
    const unsigned short* __restrict__ A, const unsigned short* __restrict__ B,
    const float* __restrict__ bias, unsigned short* __restrict__ q_buf,
    unsigned short* __restrict__ k_buf, unsigned short* __restrict__ vt_buf) {
  gemm_body<0, 128, 192>(A, B, bias, q_buf, k_buf, vt_buf, nullptr, nullptr);
}

__global__ __launch_bounds__(256) void out_gemm(
    const unsigned short* __restrict__ A, const unsigned short* __restrict__ B,
    const float* __restrict__ bias, const float* __restrict__ x_res,
    float* __restrict__ out) {
  gemm_body<1, 128, 64>(A, B, bias, nullptr, nullptr, nullptr, x_res, out);
}

// ---------------- windowed flash attention (QBLK=32, KBLK=64) --------------
// 4 waves/block, 1 wave per (head, 32-query tile); 64-key tiles: ~5 iters
// instead of 9, 8 independent QK MFMA chains + 16 PV MFMA per LDS round-trip
// (2x ILP per dependency link), amortized mask/address overhead.
// No-max softmax; masked keys give P=0 so tail V garbage contributes 0
// (poison 0xAAAA is finite). Per-wave LDS P slices, no barriers; setprio(T5).
__global__ __launch_bounds__(256) void win_attn(
    const unsigned short* __restrict__ q_buf,
    const unsigned short* __restrict__ k_buf,
    const unsigned short* __restrict__ vt_buf,
    unsigned short* __restrict__ ctx) {
  __shared__ __align__(16) unsigned short p_lds[4][2][16 * 72];  // 64 + 8 pad
  int tid = threadIdx.x;
  int wave = tid >> 6;
  int lane = tid & 63;
  int lo = lane & 15, hi = lane >> 4;

  int id = blockIdx.x;
  int sw = (id & 7) * (512 / 8) + (id >> 3);
  int job = sw * 4 + wave;           // 2048 jobs
  int h = job >> 7;
  int q0 = (job & 127) * 32;
  const float SC = 0.18033688011112042f;  // (1/sqrt(64)) * log2(e)

  bf16x8 aq[2][2];
#pragma unroll
  for (int u = 0; u < 2; ++u) {
    const unsigned short* qrow =
        q_buf + ((size_t)h * T_SEQ + q0 + u * 16 + lo) * HDIM + hi * 8;
    aq[u][0] = *reinterpret_cast<const bf16x8*>(qrow);
    aq[u][1] = *reinterpret_cast<const bf16x8*>(qrow + 32);
  }

  float L[2][4] = {{0.f, 0.f, 0.f, 0.f}, {0.f, 0.f, 0.f, 0.f}};
  f32x4 o[2][4];
#pragma unroll
  for (int u = 0; u < 2; ++u)
#pragma unroll
    for (int n = 0; n < 4; ++n) o[u][n] = (f32x4){0.f, 0.f, 0.f, 0.f};

  int jstart = q0 - WIN; if (jstart < 0) jstart = 0;
  int jend = q0 + 32 + WIN; if (jend > T_SEQ) jend = T_SEQ;

  for (int j0 = jstart; j0 < jend; j0 += 64) {
    // ---- K 64-tile (4 sub-fragments, clamped rows; masked below) ----
    bf16x8 kc[4][2];
#pragma unroll
    for (int c = 0; c < 4; ++c) {
      int krow = j0 + c * 16 + lo;
      if (krow > T_SEQ - 1) krow = T_SEQ - 1;
      const unsigned short* kp = k_buf + ((size_t)h * T_SEQ + krow) * HDIM + hi * 8;
      kc[c][0] = *reinterpret_cast<const bf16x8*>(kp);
      kc[c][1] = *reinterpret_cast<const bf16x8*>(kp + 32);
    }
    // ---- V 64-tile (tail over-read lands in slack; nullified by P=0) ----
    bf16x8 vc[4][2];
#pragma unroll
    for (int n = 0; n < 4; ++n) {
      const unsigned short* vp =
          vt_buf + ((size_t)(h * HDIM + n * 16 + lo)) * T_SEQ + j0 + hi * 8;
      vc[n][0] = *reinterpret_cast<const bf16x8*>(vp);
      vc[n][1] = *reinterpret_cast<const bf16x8*>(vp + 32);
    }
    // ---- S = Q K^T (8 independent 2-chains), mask + exp, pack P ----
#pragma unroll
    for (int u = 0; u < 2; ++u) {
      f32x4 z[4];
      __builtin_amdgcn_s_setprio(1);
#pragma unroll
      for (int c = 0; c < 4; ++c) {
        z[c] = (f32x4){0.f, 0.f, 0.f, 0.f};
        z[c] = __builtin_amdgcn_mfma_f32_16x16x32_bf16(aq[u][0], kc[c][0], z[c], 0, 0, 0);
        z[c] = __builtin_amdgcn_mfma_f32_16x16x32_bf16(aq[u][1], kc[c][1], z[c], 0, 0, 0);
      }
      __builtin_amdgcn_s_setprio(0);
#pragma unroll
      for (int c = 0; c < 4; ++c) {
        int kj = j0 + c * 16 + lo;
#pragma unroll
        for (int jq = 0; jq < 4; ++jq) {
          int q = q0 + u * 16 + hi * 4 + jq;
          bool ok = (q - kj <= WIN) && (kj - q <= WIN);
          float p = ok ? __builtin_amdgcn_exp2f(z[c][jq] * SC) : 0.f;
          L[u][jq] += p;
          p_lds[wave][u][(hi * 4 + jq) * 72 + c * 16 + lo] = f2bf(p);
        }
      }
    }
    // per-wave LDS slice; same-wave DS ops ordered -> no barrier
    bf16x8 pa[2][2];
#pragma unroll
    for (int u = 0; u < 2; ++u) {
      pa[u][0] = *reinterpret_cast<const bf16x8*>(&p_lds[wave][u][lo * 72 + hi * 8]);
      pa[u][1] = *reinterpret_cast<const bf16x8*>(&p_lds[wave][u][lo * 72 + 32 + hi * 8]);
    }
    // ---- O += P V (16 MFMAs, independent chains per (u,n)) ----
    __builtin_amdgcn_s_setprio(1);
#pragma unroll
    for (int n = 0; n < 4; ++n) {
#pragma unroll
      for (int u = 0; u < 2; ++u) {
        o[u][n] = __builtin_amdgcn_mfma_f32_16x16x32_bf16(pa[u][0], vc[n][0], o[u][n], 0, 0, 0);
        o[u][n] = __builtin_amdgcn_mfma_f32_16x16x32_bf16(pa[u][1], vc[n][1], o[u][n], 0, 0, 0);
      }
    }
    __builtin_amdgcn_s_setprio(0);
  }
  // ---- final L reduction (within each 16-lane group) + epilogue ----
#pragma unroll
  for (int u = 0; u < 2; ++u)
#pragma unroll
    for (int jq = 0; jq < 4; ++jq) {
#pragma unroll
      for (int w = 1; w < 16; w <<= 1) L[u][jq] += __shfl_xor(L[u][jq], w, 64);
    }
#pragma unroll
  for (int u = 0; u < 2; ++u)
#pragma unroll
    for (int jq = 0; jq < 4; ++jq) {
      int t = q0 + u * 16 + hi * 4 + jq;
      float inv = 1.f / L[u][jq];
#pragma unroll
      for (int n = 0; n < 4; ++n)
        ctx[(size_t)t * DMODEL + h * HDIM + n * 16 + lo] = f2bf(o[u][n][jq] * inv);
    }
}

extern "C" void kernel_launch(void* const* d_in, const int* in_sizes, int n_in,
                              void* d_out, int out_size, void* d_ws, size_t ws_size,
                              hipStream_t stream) {
  const float* x = (const float*)d_in[0];
  const float* w_in = (const float*)d_in[1];
  const float* b_in = (const float*)d_in[2];
  const float* w_out = (const float*)d_in[3];
  const float* b_out = (const float*)d_in[4];
  float* out = (float*)d_out;

  char* ws = (char*)d_ws;
  size_t off = 0;
  auto take = [&](size_t bytes) {
    char* p = ws + off;
    off += (bytes + 255) & ~(size_t)255;
    return p;
  };
  unsigned short* x_bf = (unsigned short*)take((size_t)T_SEQ * DMODEL * 2);
  unsigned short* w_in_bf = (unsigned short*)take((size_t)3 * DMODEL * DMODEL * 2);
  unsigned short* w_out_bf = (unsigned short*)take((size_t)DMODEL * DMODEL * 2);
  unsigned short* q_buf = (unsigned short*)take((size_t)T_SEQ * DMODEL * 2);
  unsigned short* k_buf = (unsigned short*)take((size_t)T_SEQ * DMODEL * 2);
  unsigned short* vt_buf = (unsigned short*)take((size_t)T_SEQ * DMODEL * 2 + 16384);
  unsigned short* ctx = (unsigned short*)take((size_t)T_SEQ * DMODEL * 2);

  convert_all<<<2048, 256, 0, stream>>>(x, w_in, w_out, x_bf, w_in_bf, w_out_bf);

  // qkv: M=4096, N=3072, tile 128x192 -> grid (16, 32) = 512 blocks
  dim3 g1(3 * DMODEL / 192, T_SEQ / 128);
  qkv_gemm<<<g1, 256, 0, stream>>>(x_bf, w_in_bf, b_in, q_buf, k_buf, vt_buf);

  win_attn<<<512, 256, 0, stream>>>(q_buf, k_buf, vt_buf, ctx);

  // out-proj: M=4096, N=1024, tile 128x64 -> grid (16, 32) = 512 blocks
  dim3 g2(DMODEL / 64, T_SEQ / 128);
  out_gemm<<<g2, 256, 0, stream>>>(ctx, w_out_bf, b_out, x, out);
}

// Round 14
// 87.797 us; speedup vs baseline: 1.0829x; 1.0428x over previous
//
#include <hip/hip_runtime.h>

#define T_SEQ 4096
#define DMODEL 1024
#define NHEAD 16
#define HDIM 64
#define WIN 128

typedef __attribute__((ext_vector_type(8))) short bf16x8;
typedef __attribute__((ext_vector_type(4))) float f32x4;
typedef __attribute__((ext_vector_type(4))) unsigned short u16x4;

__device__ __forceinline__ unsigned short f2bf(float f) {
  unsigned int u = __builtin_bit_cast(unsigned int, f);
  return (unsigned short)((u + 0x7fffu + ((u >> 16) & 1u)) >> 16);
}

__device__ __forceinline__ void gload_lds16(const unsigned short* g,
                                            unsigned short* l) {
  __builtin_amdgcn_global_load_lds(
      (const __attribute__((address_space(1))) void*)g,
      (__attribute__((address_space(3))) void*)l, 16, 0, 0);
}

// ---------------- fused fp32 -> bf16 converts (one launch) ----------------
__global__ void convert_all(const float* __restrict__ x,
                            const float* __restrict__ w_in,
                            const float* __restrict__ w_out,
                            unsigned short* __restrict__ x_bf,
                            unsigned short* __restrict__ w_in_bf,
                            unsigned short* __restrict__ w_out_bf) {
  int stride = gridDim.x * blockDim.x;
  int t0 = blockIdx.x * blockDim.x + threadIdx.x;
#define CVT(SRC, DST, N4)                                          \
  for (int i = t0; i < (N4); i += stride) {                        \
    float4 v = reinterpret_cast<const float4*>(SRC)[i];            \
    u16x4 o;                                                       \
    o.x = f2bf(v.x); o.y = f2bf(v.y); o.z = f2bf(v.z); o.w = f2bf(v.w); \
    reinterpret_cast<u16x4*>(DST)[i] = o;                          \
  }
  CVT(x, x_bf, T_SEQ * DMODEL / 4)
  CVT(w_in, w_in_bf, 3 * DMODEL * DMODEL / 4)
  CVT(w_out, w_out_bf, DMODEL * DMODEL / 4)
#undef CVT
}

// ---- GEMM body (R7-proven, FROZEN): counted double-buffer, BK=64 ---------
// STAGE(t+1) before compute(t); one raw {vmcnt(0),lgkmcnt(0),s_barrier} per
// K-tile. LDS linear; global source pre-XOR-swizzled; reads XOR back
// (0 bank conflicts). EPI 0: qkv epilogue; EPI 1: out epilogue.
template <int EPI, int BM, int BN>
__device__ __forceinline__ void gemm_body(
    const unsigned short* __restrict__ A,
    const unsigned short* __restrict__ B,
    const float* __restrict__ bias,
    unsigned short* __restrict__ q_buf,
    unsigned short* __restrict__ k_buf,
    unsigned short* __restrict__ vt_buf,
    const float* __restrict__ x_res,
    float* __restrict__ out) {
  const int K = DMODEL;
  constexpr int NT = DMODEL / 64;           // 16 K-tiles
  constexpr int SM = BM / 2, SN = BN / 2;   // per-wave spans
  constexpr int MR = SM / 16, NR = SN / 16;
  constexpr int AL = BM / 32, BL = BN / 32; // 16B stage loads per thread
  __shared__ __align__(16) unsigned short As[2 * BM * 64];
  __shared__ __align__(16) unsigned short Bs[2 * BN * 64];

  int tid = threadIdx.x;
  int lane = tid & 63, wave = tid >> 6;
  int wr = wave >> 1, wc = wave & 1;
  int lo = lane & 15, hi = lane >> 4;
  int t0 = blockIdx.y * BM, e0 = blockIdx.x * BN;

  f32x4 acc[MR][NR];
#pragma unroll
  for (int m = 0; m < MR; ++m)
#pragma unroll
    for (int n = 0; n < NR; ++n) acc[m][n] = (f32x4){0.f, 0.f, 0.f, 0.f};

  int c8 = (tid & 7) ^ ((tid >> 3) & 7);
  int srow = tid >> 3;  // + l*32 per load
  const unsigned short* AbaseG = A + (size_t)(t0 + srow) * K + c8 * 8;
  const unsigned short* BbaseG = B + (size_t)(e0 + srow) * K + c8 * 8;
  unsigned short* ldsAu = As + wave * 512;
  unsigned short* ldsBu = Bs + wave * 512;

  auto stage = [&](int tt) {
    int k0 = tt * 64;
    int ab = (tt & 1) * (BM * 64);
    int bb = (tt & 1) * (BN * 64);
#pragma unroll
    for (int l = 0; l < AL; ++l)
      gload_lds16(AbaseG + (size_t)l * 32 * K + k0, ldsAu + l * 2048 + ab);
#pragma unroll
    for (int l = 0; l < BL; ++l)
      gload_lds16(BbaseG + (size_t)l * 32 * K + k0, ldsBu + l * 2048 + bb);
  };

  stage(0);
  asm volatile("s_waitcnt vmcnt(0) lgkmcnt(0)\n\ts_barrier" ::: "memory");

  for (int t = 0; t < NT; ++t) {
    if (t + 1 < NT) stage(t + 1);
    const unsigned short* Ab = As + (t & 1) * (BM * 64);
    const unsigned short* Bb = Bs + (t & 1) * (BN * 64);
    bf16x8 af[MR][2], bfr[NR][2];
#pragma unroll
    for (int m = 0; m < MR; ++m) {
      int row = wr * SM + m * 16 + lo;
#pragma unroll
      for (int ks = 0; ks < 2; ++ks)
        af[m][ks] = *reinterpret_cast<const bf16x8*>(
            &Ab[row * 64 + (((ks << 2) + hi) ^ (row & 7)) * 8]);
    }
#pragma unroll
    for (int n = 0; n < NR; ++n) {
      int row = wc * SN + n * 16 + lo;
#pragma unroll
      for (int ks = 0; ks < 2; ++ks)
        bfr[n][ks] = *reinterpret_cast<const bf16x8*>(
            &Bb[row * 64 + (((ks << 2) + hi) ^ (row & 7)) * 8]);
    }
#pragma unroll
    for (int ks = 0; ks < 2; ++ks)
#pragma unroll
      for (int m = 0; m < MR; ++m)
#pragma unroll
        for (int n = 0; n < NR; ++n)
          acc[m][n] = __builtin_amdgcn_mfma_f32_16x16x32_bf16(af[m][ks], bfr[n][ks],
                                                              acc[m][n], 0, 0, 0);
    asm volatile("s_waitcnt vmcnt(0) lgkmcnt(0)\n\ts_barrier" ::: "memory");
  }

  int t0w = t0 + wr * SM;
  int e0w = e0 + wc * SN;
#pragma unroll
  for (int m = 0; m < MR; ++m) {
#pragma unroll
    for (int n = 0; n < NR; ++n) {
      int e = e0w + n * 16 + lo;
      float bv = bias[e];
      if (EPI == 0) {
        int part = e >> 10;
        int h = (e >> 6) & 15;
        int d = e & 63;
        if (part == 2) {
          int t = t0w + m * 16 + hi * 4;
          u16x4 pk;
          pk.x = f2bf(acc[m][n][0] + bv);
          pk.y = f2bf(acc[m][n][1] + bv);
          pk.z = f2bf(acc[m][n][2] + bv);
          pk.w = f2bf(acc[m][n][3] + bv);
          *reinterpret_cast<u16x4*>(&vt_buf[((size_t)(h * HDIM + d)) * T_SEQ + t]) = pk;
        } else {
          unsigned short* dst = (part == 0) ? q_buf : k_buf;
#pragma unroll
          for (int jj = 0; jj < 4; ++jj) {
            int t = t0w + m * 16 + hi * 4 + jj;
            dst[((size_t)h * T_SEQ + t) * HDIM + d] = f2bf(acc[m][n][jj] + bv);
          }
        }
      } else {
#pragma unroll
        for (int jj = 0; jj < 4; ++jj) {
          int t = t0w + m * 16 + hi * 4 + jj;
          size_t idxo = (size_t)t * DMODEL + e;
          out[idxo] = acc[m][n][jj] + bv + x_res[idxo];
        }
      }
    }
  }
}

__global__ __launch_bounds__(256) void qkv_gemm(
    const unsigned short* __restrict__ A, const unsigned short* __restrict__ B,
    const float* __restrict__ bias, unsigned short* __restrict__ q_buf,
    unsigned short* __restrict__ k_buf, unsigned short* __restrict__ vt_buf) {
  gemm_body<0, 128, 192>(A, B, bias, q_buf, k_buf, vt_buf, nullptr, nullptr);
}

__global__ __launch_bounds__(256) void out_gemm(
    const unsigned short* __restrict__ A, const unsigned short* __restrict__ B,
    const float* __restrict__ bias, const float* __restrict__ x_res,
    float* __restrict__ out) {
  gemm_body<1, 128, 64>(A, B, bias, nullptr, nullptr, nullptr, x_res, out);
}

// ---------------- windowed flash attention (QBLK=64, KBLK=32) --------------
// 1 wave per (head, 64-query tile): window = 320 keys = 10 k-tiles per 64
// queries (5 tiles/32q-equiv vs 9 at QBLK=32) -> 1.8x less serial chain per
// output. 1024 waves (1/SIMD) -- R5/R10 data says per-wave serial work, not
// TLP, is what attn responds to. KBLK=32 (R13 falsified 64). No-max softmax;
// per-wave LDS P slices, no barriers; setprio around MFMA clusters (T5).
__global__ __launch_bounds__(256, 1) void win_attn(
    const unsigned short* __restrict__ q_buf,
    const unsigned short* __restrict__ k_buf,
    const unsigned short* __restrict__ vt_buf,
    unsigned short* __restrict__ ctx) {
  __shared__ __align__(16) unsigned short p_lds[4][4][16 * 40];
  int tid = threadIdx.x;
  int wave = tid >> 6;
  int lane = tid & 63;
  int lo = lane & 15, hi = lane >> 4;

  int id = blockIdx.x;
  int sw = (id & 7) * 32 + (id >> 3);  // 256 blocks, bijective
  int job = sw * 4 + wave;             // 1024 jobs
  int h = job >> 6;                    // 64 q-tiles (of 64) per head
  int q0 = (job & 63) * 64;
  const float SC = 0.18033688011112042f;  // (1/sqrt(64)) * log2(e)

  bf16x8 aq[4][2];
#pragma unroll
  for (int u = 0; u < 4; ++u) {
    const unsigned short* qrow =
        q_buf + ((size_t)h * T_SEQ + q0 + u * 16 + lo) * HDIM + hi * 8;
    aq[u][0] = *reinterpret_cast<const bf16x8*>(qrow);
    aq[u][1] = *reinterpret_cast<const bf16x8*>(qrow + 32);
  }

  float L[4][4];
  f32x4 o[4][4];
#pragma unroll
  for (int u = 0; u < 4; ++u)
#pragma unroll
    for (int n = 0; n < 4; ++n) {
      o[u][n] = (f32x4){0.f, 0.f, 0.f, 0.f};
      L[u][n] = 0.f;
    }

  int jstart = q0 - WIN; if (jstart < 0) jstart = 0;
  int jend = q0 + 64 + WIN; if (jend > T_SEQ) jend = T_SEQ;

  for (int j0 = jstart; j0 < jend; j0 += 32) {
    // ---- K tile (2 16-row frags, clamped; masked below) ----
    bf16x8 kc[2][2];
#pragma unroll
    for (int c = 0; c < 2; ++c) {
      int krow = j0 + c * 16 + lo;
      if (krow > T_SEQ - 1) krow = T_SEQ - 1;
      const unsigned short* kp = k_buf + ((size_t)h * T_SEQ + krow) * HDIM + hi * 8;
      kc[c][0] = *reinterpret_cast<const bf16x8*>(kp);
      kc[c][1] = *reinterpret_cast<const bf16x8*>(kp + 32);
    }
    // ---- V tile (independent of S; issue early) ----
    bf16x8 vc[4];
#pragma unroll
    for (int n = 0; n < 4; ++n)
      vc[n] = *reinterpret_cast<const bf16x8*>(
          vt_buf + ((size_t)(h * HDIM + n * 16 + lo)) * T_SEQ + j0 + hi * 8);
    // ---- S = Q K^T (8 independent 2-chains over u,c), mask+exp, pack ----
#pragma unroll
    for (int u = 0; u < 4; ++u) {
      f32x4 z[2];
      __builtin_amdgcn_s_setprio(1);
#pragma unroll
      for (int c = 0; c < 2; ++c) {
        z[c] = (f32x4){0.f, 0.f, 0.f, 0.f};
        z[c] = __builtin_amdgcn_mfma_f32_16x16x32_bf16(aq[u][0], kc[c][0], z[c], 0, 0, 0);
        z[c] = __builtin_amdgcn_mfma_f32_16x16x32_bf16(aq[u][1], kc[c][1], z[c], 0, 0, 0);
      }
      __builtin_amdgcn_s_setprio(0);
#pragma unroll
      for (int c = 0; c < 2; ++c) {
        int kj = j0 + c * 16 + lo;
#pragma unroll
        for (int jq = 0; jq < 4; ++jq) {
          int q = q0 + u * 16 + hi * 4 + jq;
          bool ok = (q - kj <= WIN) && (kj - q <= WIN);
          float p = ok ? __builtin_amdgcn_exp2f(z[c][jq] * SC) : 0.f;
          L[u][jq] += p;
          p_lds[wave][u][(hi * 4 + jq) * 40 + c * 16 + lo] = f2bf(p);
        }
      }
    }
    // per-wave LDS slice; same-wave DS ops ordered -> no barrier
    bf16x8 pa[4];
#pragma unroll
    for (int u = 0; u < 4; ++u)
      pa[u] = *reinterpret_cast<const bf16x8*>(&p_lds[wave][u][lo * 40 + hi * 8]);
    // ---- O += P V (16 independent MFMAs) ----
    __builtin_amdgcn_s_setprio(1);
#pragma unroll
    for (int n = 0; n < 4; ++n)
#pragma unroll
      for (int u = 0; u < 4; ++u)
        o[u][n] = __builtin_amdgcn_mfma_f32_16x16x32_bf16(pa[u], vc[n], o[u][n], 0, 0, 0);
    __builtin_amdgcn_s_setprio(0);
  }
  // ---- final L reduction (within each 16-lane group) + epilogue ----
#pragma unroll
  for (int u = 0; u < 4; ++u)
#pragma unroll
    for (int jq = 0; jq < 4; ++jq) {
#pragma unroll
      for (int w = 1; w < 16; w <<= 1) L[u][jq] += __shfl_xor(L[u][jq], w, 64);
    }
#pragma unroll
  for (int u = 0; u < 4; ++u)
#pragma unroll
    for (int jq = 0; jq < 4; ++jq) {
      int t = q0 + u * 16 + hi * 4 + jq;
      float inv = 1.f / L[u][jq];
#pragma unroll
      for (int n = 0; n < 4; ++n)
        ctx[(size_t)t * DMODEL + h * HDIM + n * 16 + lo] = f2bf(o[u][n][jq] * inv);
    }
}

extern "C" void kernel_launch(void* const* d_in, const int* in_sizes, int n_in,
                              void* d_out, int out_size, void* d_ws, size_t ws_size,
                              hipStream_t stream) {
  const float* x = (const float*)d_in[0];
  const float* w_in = (const float*)d_in[1];
  const float* b_in = (const float*)d_in[2];
  const float* w_out = (const float*)d_in[3];
  const float* b_out = (const float*)d_in[4];
  float* out = (float*)d_out;

  char* ws = (char*)d_ws;
  size_t off = 0;
  auto take = [&](size_t bytes) {
    char* p = ws + off;
    off += (bytes + 255) & ~(size_t)255;
    return p;
  };
  unsigned short* x_bf = (unsigned short*)take((size_t)T_SEQ * DMODEL * 2);
  unsigned short* w_in_bf = (unsigned short*)take((size_t)3 * DMODEL * DMODEL * 2);
  unsigned short* w_out_bf = (unsigned short*)take((size_t)DMODEL * DMODEL * 2);
  unsigned short* q_buf = (unsigned short*)take((size_t)T_SEQ * DMODEL * 2);
  unsigned short* k_buf = (unsigned short*)take((size_t)T_SEQ * DMODEL * 2);
  unsigned short* vt_buf = (unsigned short*)take((size_t)T_SEQ * DMODEL * 2 + 8192);
  unsigned short* ctx = (unsigned short*)take((size_t)T_SEQ * DMODEL * 2);

  convert_all<<<2048, 256, 0, stream>>>(x, w_in, w_out, x_bf, w_in_bf, w_out_bf);

  // qkv: M=4096, N=3072, tile 128x192 -> grid (16, 32) = 512 blocks
  dim3 g1(3 * DMODEL / 192, T_SEQ / 128);
  qkv_gemm<<<g1, 256, 0, stream>>>(x_bf, w_in_bf, b_in, q_buf, k_buf, vt_buf);

  win_attn<<<256, 256, 0, stream>>>(q_buf, k_buf, vt_buf, ctx);

  // out-proj: M=4096, N=1024, tile 128x64 -> grid (16, 32) = 512 blocks
  dim3 g2(DMODEL / 64, T_SEQ / 128);
  out_gemm<<<g2, 256, 0, stream>>>(ctx, w_out_bf, b_out, x, out);
}